// Round 15
// baseline (34.963 us; speedup 1.0000x reference)
//
#include <hip/hip_runtime.h>
#include <hip/hip_bf16.h>

// Problem constants: (8, 2048, 128) fp32 x2 -> (8, 2048, 2048) fp32
#define BATCH 8
#define RROWS 2048
#define DDIM  128
#define BM    128
#define BN    64

using f32x4 = __attribute__((ext_vector_type(4))) float;
using s16x8 = __attribute__((ext_vector_type(8))) short;
using u16x4 = __attribute__((ext_vector_type(4))) unsigned short;

#define SCHED0() __builtin_amdgcn_sched_barrier(0)
#define LGKM0()  asm volatile("s_waitcnt lgkmcnt(0)" ::: "memory")

// fp32 -> bf16 round-to-nearest-even (inputs are finite normals)
__device__ __forceinline__ unsigned short f2bf(float f) {
    unsigned int u = __builtin_bit_cast(unsigned int, f);
    u += 0x7fffu + ((u >> 16) & 1u);
    return (unsigned short)(u >> 16);
}

// One lane's float4 slice of a 32-lane row -> L2-normalized bf16 quad.
__device__ __forceinline__ u16x4 norm_cvt(float4 v) {
    float s = v.x * v.x + v.y * v.y + v.z * v.z + v.w * v.w;
    #pragma unroll
    for (int i = 1; i <= 16; i <<= 1) s += __shfl_xor(s, i);
    const float r = rsqrtf(fmaxf(s, 1e-8f));
    u16x4 p;
    p[0] = f2bf(v.x * r); p[1] = f2bf(v.y * r);
    p[2] = f2bf(v.z * r); p[3] = f2bf(v.w * r);
    return p;
}

// ---------------- R12 + row-split waves + wave-private transpose epilogue ----------------
// Grid 512 (lid&7 = batch = XCD). A-fragments in registers. Waves split by ROWS
// (wave owns 32 full rows x 64 cols), so the C-tile transpose for full-line
// stores is wave-private: acc -> 8KB private Cs -> lgkmcnt(0) (same-wave, NO
// s_barrier) -> row-major readback -> 8 x global_store_dwordx4, each covering
// 4 rows x 256 B CONTIGUOUS (2 full 128B lines per row). Tests the half-line
// write-efficiency theory at zero structural cost (vs R13's +2 barriers).
__global__ __launch_bounds__(256, 2) void fused_kernel(const float* __restrict__ m1,
                                                       const float* __restrict__ m2,
                                                       float* __restrict__ out) {
    __shared__ __align__(16) char lds[65536];
    char* Bs0 = lds;                       // 16 KB (A staged over Bs0+Bs1 in prologue)
    char* Bs1 = lds + 16384;               // 16 KB
    char* Cs  = lds + 32768;               // 32 KB: 4 waves x 8 KB private transpose slices

    const int tid    = threadIdx.x;
    const int wave   = tid >> 6;
    const int lane   = tid & 63;
    const int l32    = tid & 31;
    const int grp    = tid >> 5;           // 0..7 : row-group (rows ≡ grp mod 8)
    const int lid    = blockIdx.x;
    const int b      = lid & 7;            // batch == XCD
    const int idx    = lid >> 3;           // 0..63
    const int tile_m = idx >> 2;           // 0..15
    const int q      = idx & 3;            // n-quarter (512 cols, 8 rounds of 64)

    const float* gA = m1 + ((size_t)b * RROWS + (size_t)tile_m * BM) * DDIM;
    const float* gB = m2 + ((size_t)b * RROWS + (size_t)q * 512) * DDIM;

    // ---- Prologue (R12) ----
    float4 rb[8];
    #pragma unroll
    for (int i = 0; i < 8; ++i)
        rb[i] = *(const float4*)(gB + (size_t)(i * 8 + grp) * DDIM + l32 * 4);

    // Normalize A panel (128 rows) -> 32 KB LDS (transient staging), swizzled.
    #pragma unroll
    for (int s = 0; s < 16; ++s) {
        const int r = s * 8 + grp;
        const float4 va = *(const float4*)(gA + (size_t)r * DDIM + l32 * 4);
        const u16x4 pa = norm_cvt(va);
        const int off = r * 256 + l32 * 8;
        *(u16x4*)(lds + (off ^ ((r & 7) << 4))) = pa;
    }
    LGKM0();
    __builtin_amdgcn_s_barrier();

    // Row-split wave geometry: wave owns rows [wave*32, wave*32+32), cols 0..63.
    const int lrow = lane & 15;
    const int kb   = (lane >> 4) * 8;

    // Pull this wave's 8 A fragments into registers (rows wave*32 + m*16 + lrow).
    s16x8 af[4][2];                        // [kk][m] — compile-time indices only
    #pragma unroll
    for (int kk = 0; kk < 4; ++kk) {
        const int k = kk * 32 + kb;
        #pragma unroll
        for (int m = 0; m < 2; ++m) {
            const int ra   = wave * 32 + m * 16 + lrow;
            const int offa = ra * 256 + k * 2;
            af[kk][m] = *(const s16x8*)(lds + (offa ^ ((ra & 7) << 4)));
        }
    }
    LGKM0();                               // fragment reads complete
    __builtin_amdgcn_s_barrier();          // before Bs0 overwrites the staging

    // Process B(0) -> Bs0, prefetch B(1).
    #pragma unroll
    for (int i = 0; i < 8; ++i) {
        const int r = i * 8 + grp;
        const u16x4 pb = norm_cvt(rb[i]);
        const int off = r * 256 + l32 * 8;
        *(u16x4*)(Bs0 + (off ^ ((r & 7) << 4))) = pb;
    }
    #pragma unroll
    for (int i = 0; i < 8; ++i)
        rb[i] = *(const float4*)(gB + (size_t)(64 + i * 8 + grp) * DDIM + l32 * 4);
    LGKM0();
    __builtin_amdgcn_s_barrier();

    char* Csw = Cs + wave * 8192;          // this wave's private 32x64 f32 slice
    float* gout_base = out + (size_t)b * RROWS * RROWS
                           + (size_t)(tile_m * BM + wave * 32) * RROWS + (size_t)q * 512;

    #pragma unroll
    for (int t = 0; t < 8; ++t) {
        const char* Bs  = (t & 1) ? Bs1 : Bs0;
        char*       Bsn = (t & 1) ? Bs0 : Bs1;

        // ---- MFMA: A from registers, B from LDS (16 ds_read_b128/wave) ----
        f32x4 acc[2][4];
        #pragma unroll
        for (int m = 0; m < 2; ++m)
            #pragma unroll
            for (int n = 0; n < 4; ++n)
                acc[m][n] = f32x4{0.f, 0.f, 0.f, 0.f};

        #pragma unroll
        for (int kk = 0; kk < 4; ++kk) {
            const int k = kk * 32 + kb;
            s16x8 bfr[4];
            #pragma unroll
            for (int n = 0; n < 4; ++n) {
                const int rbr  = n * 16 + lrow;
                const int offb = rbr * 256 + k * 2;
                bfr[n] = *(const s16x8*)(Bs + (offb ^ ((rbr & 7) << 4)));
            }
            #pragma unroll
            for (int m = 0; m < 2; ++m)
                #pragma unroll
                for (int n = 0; n < 4; ++n)
                    acc[m][n] = __builtin_amdgcn_mfma_f32_16x16x32_bf16(af[kk][m], bfr[n], acc[m][n], 0, 0, 0);
        }

        // ---- Wave-private transpose: acc -> Csw (swizzled; 2-way max = free) ----
        // C/D: local row = m*16 + (lane>>4)*4 + reg, col = n*16 + (lane&15).
        #pragma unroll
        for (int m = 0; m < 2; ++m) {
            #pragma unroll
            for (int n = 0; n < 4; ++n) {
                const int col = n * 16 + lrow;
                #pragma unroll
                for (int reg = 0; reg < 4; ++reg) {
                    const int rl  = m * 16 + (lane >> 4) * 4 + reg;
                    const int off = rl * 256 + col * 4;
                    *(float*)(Csw + (off ^ ((rl & 7) << 4))) = acc[m][n][reg];
                }
            }
        }
        LGKM0();                           // same-wave ordering only — no barrier
        SCHED0();

        // ---- Full-line stores: 8 x dwordx4, each 4 rows x 256 B contiguous ----
        float* gout = gout_base + t * BN;
        #pragma unroll
        for (int i = 0; i < 8; ++i) {
            const int rl  = i * 4 + (lane >> 4);
            const int c4  = lane & 15;
            const int off = rl * 256 + c4 * 16;
            const f32x4 v = *(const f32x4*)(Csw + (off ^ ((rl & 7) << 4)));
            *(f32x4*)(gout + (size_t)rl * RROWS + c4 * 4) = v;
        }

        if (t < 7) {
            // Process AFTER the stores (R12-proven): auto-waitcnt for rb counts
            // the newer stores -> store queue stays full across the barrier.
            SCHED0();
            #pragma unroll
            for (int i = 0; i < 8; ++i) {
                const int r = i * 8 + grp;
                const u16x4 pb = norm_cvt(rb[i]);
                const int off = r * 256 + l32 * 8;
                *(u16x4*)(Bsn + (off ^ ((r & 7) << 4))) = pb;
            }
            // Prefetch B(t+2) fp32 (XCD-L2 hit).
            if (t < 6) {
                #pragma unroll
                for (int i = 0; i < 8; ++i)
                    rb[i] = *(const float4*)(gB + (size_t)((t + 2) * 64 + i * 8 + grp) * DDIM + l32 * 4);
            }
            LGKM0();                        // publish ds_writes
            __builtin_amdgcn_s_barrier();
        }
    }
}

extern "C" void kernel_launch(void* const* d_in, const int* in_sizes, int n_in,
                              void* d_out, int out_size, void* d_ws, size_t ws_size,
                              hipStream_t stream) {
    (void)in_sizes; (void)n_in; (void)out_size; (void)d_ws; (void)ws_size;
    const float* m1 = (const float*)d_in[0];
    const float* m2 = (const float*)d_in[1];
    float* out = (float*)d_out;

    fused_kernel<<<dim3(BATCH * (RROWS / BM) * (RROWS / BN / 8)), dim3(256), 0, stream>>>(m1, m2, out);
}

// Round 16
// 32.645 us; speedup vs baseline: 1.0710x; 1.0710x over previous
//
#include <hip/hip_runtime.h>
#include <hip/hip_bf16.h>

// Problem constants: (8, 2048, 128) fp32 x2 -> (8, 2048, 2048) fp32
#define BATCH 8
#define RROWS 2048
#define DDIM  128
#define BM    128
#define BN    64

using f32x4 = __attribute__((ext_vector_type(4))) float;
using s16x8 = __attribute__((ext_vector_type(8))) short;
using u16x4 = __attribute__((ext_vector_type(4))) unsigned short;

#define SCHED0() __builtin_amdgcn_sched_barrier(0)
#define LGKM0()  asm volatile("s_waitcnt lgkmcnt(0)" ::: "memory")

// fp32 -> bf16 round-to-nearest-even (inputs are finite normals)
__device__ __forceinline__ unsigned short f2bf(float f) {
    unsigned int u = __builtin_bit_cast(unsigned int, f);
    u += 0x7fffu + ((u >> 16) & 1u);
    return (unsigned short)(u >> 16);
}

// One lane's float4 slice of a 32-lane row -> L2-normalized bf16 quad.
__device__ __forceinline__ u16x4 norm_cvt(float4 v) {
    float s = v.x * v.x + v.y * v.y + v.z * v.z + v.w * v.w;
    #pragma unroll
    for (int i = 1; i <= 16; i <<= 1) s += __shfl_xor(s, i);
    const float r = rsqrtf(fmaxf(s, 1e-8f));
    u16x4 p;
    p[0] = f2bf(v.x * r); p[1] = f2bf(v.y * r);
    p[2] = f2bf(v.z * r); p[3] = f2bf(v.w * r);
    return p;
}

// ---------------- Best-known kernel (R12): fused, persistent-tile, A-in-registers ----------------
// Grid 512 (lid&7 = batch = XCD; per-XCD input set L2-resident). launch_bounds(256,2):
// VGPR budget 256 covers af(64)+rb(32)+acc(32)+addressing with no spill.
// Prologue: normalize A panel through LDS (transient), pull 16 A-fragments/wave
// into registers; LDS then serves only the B double-buffer (2x16K).
// Main loop (8 rounds): MFMA (8 ds_read_b128/wave) -> scalar stores
// (fire-and-forget; L2 write-combines the 64B segments) -> process B(t+1) from
// prefetched regs -> prefetch B(t+2) -> lgkm + raw s_barrier. No vmcnt(0)
// mid-loop: the store queue stays full across round boundaries.
// Measured 32.8 us; model: 168 MB HBM / (0.85 x 6.76 TB/s) + head + tail = 32.9 us.
__global__ __launch_bounds__(256, 2) void fused_kernel(const float* __restrict__ m1,
                                                       const float* __restrict__ m2,
                                                       float* __restrict__ out) {
    __shared__ __align__(16) char lds[32768];   // B dbuf 2x16K; A staged here in prologue
    char* Bs0 = lds;
    char* Bs1 = lds + 16384;

    const int tid    = threadIdx.x;
    const int wave   = tid >> 6;
    const int lane   = tid & 63;
    const int l32    = tid & 31;
    const int grp    = tid >> 5;           // 0..7 : row-group (rows ≡ grp mod 8)
    const int lid    = blockIdx.x;
    const int b      = lid & 7;            // batch == XCD
    const int idx    = lid >> 3;           // 0..63
    const int tile_m = idx >> 2;           // 0..15
    const int q      = idx & 3;            // n-quarter (512 cols, 8 rounds of 64)

    const float* gA = m1 + ((size_t)b * RROWS + (size_t)tile_m * BM) * DDIM;
    const float* gB = m2 + ((size_t)b * RROWS + (size_t)q * 512) * DDIM;

    // ---- Prologue ----
    // Issue B(0) fp32 loads first (latency hides under A-normalize).
    float4 rb[8];
    #pragma unroll
    for (int i = 0; i < 8; ++i)
        rb[i] = *(const float4*)(gB + (size_t)(i * 8 + grp) * DDIM + l32 * 4);

    // Normalize A panel (128 rows) -> full 32 KB LDS, swizzled (transient).
    #pragma unroll
    for (int s = 0; s < 16; ++s) {
        const int r = s * 8 + grp;
        const float4 va = *(const float4*)(gA + (size_t)r * DDIM + l32 * 4);
        const u16x4 pa = norm_cvt(va);
        const int off = r * 256 + l32 * 8;
        *(u16x4*)(lds + (off ^ ((r & 7) << 4))) = pa;
    }
    LGKM0();
    __builtin_amdgcn_s_barrier();

    // Pull this wave's 16 A fragments into registers (live for whole kernel).
    const int wr   = wave >> 1;            // 0..1 : 64-row half
    const int wc   = wave & 1;             // 0..1 : 32-col half
    const int lrow = lane & 15;
    const int kb   = (lane >> 4) * 8;

    s16x8 af[4][4];                        // [kk][m] — compile-time indices only
    #pragma unroll
    for (int kk = 0; kk < 4; ++kk) {
        const int k = kk * 32 + kb;
        #pragma unroll
        for (int m = 0; m < 4; ++m) {
            const int ra   = wr * 64 + m * 16 + lrow;
            const int offa = ra * 256 + k * 2;
            af[kk][m] = *(const s16x8*)(lds + (offa ^ ((ra & 7) << 4)));
        }
    }
    LGKM0();                               // fragment reads complete
    __builtin_amdgcn_s_barrier();          // before Bs0 overwrites the staging

    // Process B(0) -> Bs0, prefetch B(1).
    #pragma unroll
    for (int i = 0; i < 8; ++i) {
        const int r = i * 8 + grp;
        const u16x4 pb = norm_cvt(rb[i]);
        const int off = r * 256 + l32 * 8;
        *(u16x4*)(Bs0 + (off ^ ((r & 7) << 4))) = pb;
    }
    #pragma unroll
    for (int i = 0; i < 8; ++i)
        rb[i] = *(const float4*)(gB + (size_t)(64 + i * 8 + grp) * DDIM + l32 * 4);
    LGKM0();
    __builtin_amdgcn_s_barrier();

    float* gout_base = out + (size_t)b * RROWS * RROWS
                           + (size_t)(tile_m * BM) * RROWS + (size_t)q * 512;

    #pragma unroll
    for (int t = 0; t < 8; ++t) {
        const char* Bs  = (t & 1) ? Bs1 : Bs0;
        char*       Bsn = (t & 1) ? Bs0 : Bs1;

        // ---- MFMA: A from registers, B from LDS (8 ds_read_b128/wave) ----
        f32x4 acc[4][2];
        #pragma unroll
        for (int m = 0; m < 4; ++m)
            #pragma unroll
            for (int n = 0; n < 2; ++n)
                acc[m][n] = f32x4{0.f, 0.f, 0.f, 0.f};

        #pragma unroll
        for (int kk = 0; kk < 4; ++kk) {
            const int k = kk * 32 + kb;
            s16x8 bfr[2];
            #pragma unroll
            for (int n = 0; n < 2; ++n) {
                const int rbr  = wc * 32 + n * 16 + lrow;
                const int offb = rbr * 256 + k * 2;
                bfr[n] = *(const s16x8*)(Bs + (offb ^ ((rbr & 7) << 4)));
            }
            #pragma unroll
            for (int m = 0; m < 4; ++m)
                #pragma unroll
                for (int n = 0; n < 2; ++n)
                    acc[m][n] = __builtin_amdgcn_mfma_f32_16x16x32_bf16(af[kk][m], bfr[n], acc[m][n], 0, 0, 0);
        }

        // ---- Stores (scalar, fire-and-forget; L2 write-combines) ----
        // C/D layout: col = lane&15, row = (lane>>4)*4 + reg.
        float* gout = gout_base + t * BN;
        const int orow0 = wr * 64 + (lane >> 4) * 4;
        const int ocol0 = wc * 32 + lrow;
        #pragma unroll
        for (int m = 0; m < 4; ++m) {
            #pragma unroll
            for (int n = 0; n < 2; ++n) {
                const int col = ocol0 + n * 16;
                #pragma unroll
                for (int reg = 0; reg < 4; ++reg) {
                    const int row = orow0 + m * 16 + reg;
                    gout[(size_t)row * RROWS + col] = acc[m][n][reg];
                }
            }
        }

        if (t < 7) {
            // Process AFTER the stores: auto-waitcnt for rb counts the newer
            // stores -> store queue stays full across the barrier.
            SCHED0();
            #pragma unroll
            for (int i = 0; i < 8; ++i) {
                const int r = i * 8 + grp;
                const u16x4 pb = norm_cvt(rb[i]);
                const int off = r * 256 + l32 * 8;
                *(u16x4*)(Bsn + (off ^ ((r & 7) << 4))) = pb;
            }
            // Prefetch B(t+2) fp32 (XCD-L2 hit).
            if (t < 6) {
                #pragma unroll
                for (int i = 0; i < 8; ++i)
                    rb[i] = *(const float4*)(gB + (size_t)((t + 2) * 64 + i * 8 + grp) * DDIM + l32 * 4);
            }
            LGKM0();                        // publish ds_writes
            __builtin_amdgcn_s_barrier();
        }
    }
}

extern "C" void kernel_launch(void* const* d_in, const int* in_sizes, int n_in,
                              void* d_out, int out_size, void* d_ws, size_t ws_size,
                              hipStream_t stream) {
    (void)in_sizes; (void)n_in; (void)out_size; (void)d_ws; (void)ws_size;
    const float* m1 = (const float*)d_in[0];
    const float* m2 = (const float*)d_in[1];
    float* out = (float*)d_out;

    fused_kernel<<<dim3(BATCH * (RROWS / BM) * (RROWS / BN / 8)), dim3(256), 0, stream>>>(m1, m2, out);
}